// Round 6
// baseline (565.773 us; speedup 1.0000x reference)
//
#include <hip/hip_runtime.h>
#include <hip/hip_bf16.h>

#define BB 4
#define CC 512
#define NN 4096
#define DD 64   // C8

typedef __attribute__((ext_vector_type(8))) short short8;
typedef __attribute__((ext_vector_type(4))) short short4v;
typedef __attribute__((ext_vector_type(4))) float floatx4;

static __device__ __forceinline__ short f2bf(float f) {
  __hip_bfloat16 h = __float2bfloat16(f);
  return *reinterpret_cast<short*>(&h);
}

static __device__ __forceinline__ floatx4 mfma16(short8 a, short8 b, floatx4 c) {
  return __builtin_amdgcn_mfma_f32_16x16x32_bf16(a, b, c, 0, 0, 0);
}

// ---------------------------------------------------------------------------
// Kernel 0: convert W (Wq rows 0-63, Wk 64-127, Wv 128-639) to bf16 [640][512]
// ---------------------------------------------------------------------------
__global__ void wconv_kernel(const float* __restrict__ Wq, const float* __restrict__ Wk,
                             const float* __restrict__ Wv, short* __restrict__ Wb) {
  int i = blockIdx.x * 256 + threadIdx.x;   // 640*512 = 327680
  int row = i >> 9, c = i & 511;
  float v;
  if (row < 64)        v = Wq[(row << 9) | c];
  else if (row < 128)  v = Wk[((row - 64) << 9) | c];
  else                 v = Wv[((row - 128) << 9) | c];
  Wb[i] = f2bf(v);
}

// ---------------------------------------------------------------------------
// Kernel 1: QKV as 128x128-tile GEMM.  C[m=b*N+n][dout] = x^T @ W^T + bias
//   M = 16384 (128 m-tiles), N = 640 (5 j-tiles), K = 512 (8 steps of 64)
// 512 threads = 8 waves (2m x 4j); wave owns 64m x 32j.
// A-tile (x^T, bf16) staged in LDS; B-frags read straight from Wb (L2).
// ---------------------------------------------------------------------------
__global__ __launch_bounds__(512, 4) void qkv_kernel(
    const float* __restrict__ x, const short* __restrict__ Wb,
    const float* __restrict__ bq, const float* __restrict__ bk,
    const float* __restrict__ bv,
    short* __restrict__ qb, short* __restrict__ kb, short* __restrict__ vb) {
  const int bid = blockIdx.x;
  const int jt = bid % 5;
  const int mt = bid / 5;
  const int b  = mt >> 5;
  const int n0 = (mt & 31) << 7;
  const int tid = threadIdx.x;
  const int w = tid >> 6, lane = tid & 63;
  const int arow = lane & 15, grp = lane >> 4;
  const int wm = w >> 2, wj = w & 3;

  __shared__ short xs[128][72];   // [m][k], +8 pad

  const float* xb = x + (size_t)b * CC * NN;
  // staging: thread owns 4c x 4n micro-block
  const int n4l = (tid & 31) << 2;
  const int c4  = (tid >> 5) << 2;

  floatx4 ld[4];
  #pragma unroll
  for (int i = 0; i < 4; ++i)
    ld[i] = *(const floatx4*)(xb + (size_t)(c4 + i) * NN + n0 + n4l);

  floatx4 acc[4][2];
  #pragma unroll
  for (int i = 0; i < 4; ++i)
    #pragma unroll
    for (int j = 0; j < 2; ++j) acc[i][j] = (floatx4){0.f, 0.f, 0.f, 0.f};

  for (int kk = 0; kk < 8; ++kk) {
    __syncthreads();   // previous step's reads done
    // transpose-write regs -> xs (4 x b64)
    #pragma unroll
    for (int j = 0; j < 4; ++j) {
      short4v pk;
      #pragma unroll
      for (int i = 0; i < 4; ++i) pk[i] = f2bf(ld[i][j]);
      *(short4v*)&xs[n4l + j][c4] = pk;
    }
    __syncthreads();
    // prefetch next k-step into regs (overlaps frag reads + MFMA)
    if (kk < 7) {
      #pragma unroll
      for (int i = 0; i < 4; ++i)
        ld[i] = *(const floatx4*)(xb + (size_t)((kk + 1) * 64 + c4 + i) * NN + n0 + n4l);
    }
    #pragma unroll
    for (int ks = 0; ks < 2; ++ks) {
      short8 pa[4];
      #pragma unroll
      for (int ms = 0; ms < 4; ++ms)
        pa[ms] = *(const short8*)&xs[wm * 64 + ms * 16 + arow][ks * 32 + grp * 8];
      #pragma unroll
      for (int js = 0; js < 2; ++js) {
        const short* wp = Wb + (size_t)(jt * 128 + wj * 32 + js * 16 + arow) * CC
                        + kk * 64 + ks * 32 + grp * 8;
        short8 bfr = *(const short8*)wp;
        #pragma unroll
        for (int ms = 0; ms < 4; ++ms)
          acc[ms][js] = mfma16(pa[ms], bfr, acc[ms][js]);
      }
    }
  }

  #pragma unroll
  for (int js = 0; js < 2; ++js) {
    int dout = jt * 128 + wj * 32 + js * 16 + arow;
    float bias = (dout < 64) ? bq[dout] : (dout < 128) ? bk[dout - 64] : bv[dout - 128];
    #pragma unroll
    for (int ms = 0; ms < 4; ++ms) {
      int n = n0 + wm * 64 + ms * 16 + grp * 4;
      floatx4 a = acc[ms][js];
      if (dout < 64) {
        #pragma unroll
        for (int r = 0; r < 4; ++r)
          qb[((size_t)b * NN + n + r) * DD + dout] = f2bf(a[r] + bias);
      } else if (dout < 128) {
        #pragma unroll
        for (int r = 0; r < 4; ++r)
          kb[((size_t)b * NN + n + r) * DD + (dout - 64)] = f2bf(a[r] + bias);
      } else {
        short4v pk;
        #pragma unroll
        for (int r = 0; r < 4; ++r) pk[r] = f2bf(a[r] + bias);
        *(short4v*)(vb + ((size_t)b * CC + (dout - 128)) * NN + n) = pk;
      }
    }
  }
}

// ---------------------------------------------------------------------------
// Kernel 2: fused attention, self-normalizing, XCD-pinned.
// blockIdx = xcd + 8*slot; xcd = 2*b + ch  -> v/q/k slice lives in that XCD's L2.
// Block: m-tile 64, c-half 256. 8 waves. 3-buffer P pipeline:
//   iter i: issue v(i) loads; compute P1(i+1) -> pb[(i+1)%3]; BAR;
//           P2(i): pa <- pb[i%3], 16 MFMA with v(i).
// pbuf XOR-swizzled (row-major [64][64] bf16, byte ^= (row&7)<<4).
// ---------------------------------------------------------------------------
__global__ __launch_bounds__(512, 4) void attn_kernel(
    const short* __restrict__ qb, const short* __restrict__ kb,
    const short* __restrict__ vb, const float* __restrict__ x,
    const float* __restrict__ gamma, float* __restrict__ out) {
  const int bid = blockIdx.x;
  const int xcd = bid & 7;
  const int b = xcd >> 1, ch = xcd & 1;
  const int m0 = (bid >> 3) << 6;
  const int tid = threadIdx.x;
  const int w = tid >> 6, lane = tid & 63;
  const int arow = lane & 15, grp = lane >> 4;
  const int nsub = w & 3;    // phase1: n-subtile
  const int mh = w >> 2;     // both phases: m-half (32 rows)
  const int wc = w & 3;      // phase2: c-quarter (64 ch)

  __shared__ short pbuf[3][64 * 64];
  __shared__ float dsum[4][64];

  const short* qB = qb + (size_t)b * NN * DD;
  const short* kB = kb + (size_t)b * NN * DD;
  const short* vB = vb + ((size_t)b * CC + ch * 256) * NN;

  // hoisted k fragments for this wave's two m-tiles
  short8 afr[2][2];
  #pragma unroll
  for (int h = 0; h < 2; ++h) {
    const short* kr = kB + (size_t)(m0 + mh * 32 + h * 16 + arow) * DD;
    afr[h][0] = *(const short8*)(kr + grp * 8);
    afr[h][1] = *(const short8*)(kr + 32 + grp * 8);
  }

  floatx4 acc[2][4];   // [ms][cs]
  #pragma unroll
  for (int i = 0; i < 2; ++i)
    #pragma unroll
    for (int j = 0; j < 4; ++j) acc[i][j] = (floatx4){0.f, 0.f, 0.f, 0.f};
  float dl[2][4];
  #pragma unroll
  for (int h = 0; h < 2; ++h)
    #pragma unroll
    for (int r = 0; r < 4; ++r) dl[h][r] = 0.f;

  short8 qa0, qa1;
  {
    const short* qr = qB + (size_t)(nsub * 16 + arow) * DD + grp * 8;
    qa0 = *(const short8*)(qr);
    qa1 = *(const short8*)(qr + 32);
  }

  // P1(0) -> pbuf[0]
  #pragma unroll
  for (int h = 0; h < 2; ++h) {
    floatx4 s4 = (floatx4){0.f, 0.f, 0.f, 0.f};
    s4 = mfma16(afr[h][0], qa0, s4);
    s4 = mfma16(afr[h][1], qa1, s4);
    int mrow = mh * 32 + h * 16 + grp * 4;
    #pragma unroll
    for (int r = 0; r < 4; ++r) {
      float p = __expf(s4[r]);
      dl[h][r] += p;
      int row = mrow + r;
      pbuf[0][row * 64 + ((nsub * 16 + arow) ^ ((row & 7) << 3))] = f2bf(p);
    }
  }
  {
    const short* qr = qB + (size_t)(64 + nsub * 16 + arow) * DD + grp * 8;
    qa0 = *(const short8*)(qr);
    qa1 = *(const short8*)(qr + 32);
  }

  int cur = 0;
  for (int i = 0; i < 64; ++i) {
    const int nb = i << 6;
    int nxt = cur + 1; if (nxt == 3) nxt = 0;
    // early v loads (ks=0) for this iteration
    short8 vv0[4];
    #pragma unroll
    for (int cs = 0; cs < 4; ++cs)
      vv0[cs] = *(const short8*)(vB + (size_t)(wc * 64 + cs * 16 + arow) * NN + nb + grp * 8);
    // P1(i+1)
    if (i < 63) {
      #pragma unroll
      for (int h = 0; h < 2; ++h) {
        floatx4 s4 = (floatx4){0.f, 0.f, 0.f, 0.f};
        s4 = mfma16(afr[h][0], qa0, s4);
        s4 = mfma16(afr[h][1], qa1, s4);
        int mrow = mh * 32 + h * 16 + grp * 4;
        #pragma unroll
        for (int r = 0; r < 4; ++r) {
          float p = __expf(s4[r]);
          dl[h][r] += p;
          int row = mrow + r;
          pbuf[nxt][row * 64 + ((nsub * 16 + arow) ^ ((row & 7) << 3))] = f2bf(p);
        }
      }
    }
    if (i < 62) {
      const short* qr = qB + (size_t)(nb + 128 + nsub * 16 + arow) * DD + grp * 8;
      qa0 = *(const short8*)(qr);
      qa1 = *(const short8*)(qr + 32);
    }
    __syncthreads();
    // P2(i): pa from pbuf[cur]
    short8 pa[2][2];
    #pragma unroll
    for (int ms = 0; ms < 2; ++ms) {
      int row = mh * 32 + ms * 16 + arow;
      #pragma unroll
      for (int ks = 0; ks < 2; ++ks)
        pa[ms][ks] = *(const short8*)&pbuf[cur][row * 64 + ((ks * 32 + grp * 8) ^ ((row & 7) << 3))];
    }
    short8 vv1[4];
    #pragma unroll
    for (int cs = 0; cs < 4; ++cs)
      vv1[cs] = *(const short8*)(vB + (size_t)(wc * 64 + cs * 16 + arow) * NN + nb + 32 + grp * 8);
    __builtin_amdgcn_s_setprio(1);
    #pragma unroll
    for (int cs = 0; cs < 4; ++cs)
      #pragma unroll
      for (int ms = 0; ms < 2; ++ms)
        acc[ms][cs] = mfma16(pa[ms][0], vv0[cs], acc[ms][cs]);
    #pragma unroll
    for (int cs = 0; cs < 4; ++cs)
      #pragma unroll
      for (int ms = 0; ms < 2; ++ms)
        acc[ms][cs] = mfma16(pa[ms][1], vv1[cs], acc[ms][cs]);
    __builtin_amdgcn_s_setprio(0);
    cur = nxt;
  }

  // denominator: reduce dl over the 16 arow lanes; combine 4 nsub partials in LDS
  #pragma unroll
  for (int off = 1; off < 16; off <<= 1)
    #pragma unroll
    for (int h = 0; h < 2; ++h)
      #pragma unroll
      for (int r = 0; r < 4; ++r)
        dl[h][r] += __shfl_xor(dl[h][r], off);
  if (arow == 0) {
    #pragma unroll
    for (int h = 0; h < 2; ++h)
      #pragma unroll
      for (int r = 0; r < 4; ++r)
        dsum[nsub][mh * 32 + h * 16 + grp * 4 + r] = dl[h][r];
  }
  __syncthreads();

  const float g = *gamma;
  #pragma unroll
  for (int ms = 0; ms < 2; ++ms) {
    int ml = mh * 32 + ms * 16 + grp * 4;
    floatx4 linv;
    #pragma unroll
    for (int r = 0; r < 4; ++r) {
      float l = dsum[0][ml + r] + dsum[1][ml + r] + dsum[2][ml + r] + dsum[3][ml + r];
      linv[r] = g / l;
    }
    #pragma unroll
    for (int cs = 0; cs < 4; ++cs) {
      int c = ch * 256 + wc * 64 + cs * 16 + arow;
      const float* xp = x + ((size_t)b * CC + c) * NN + m0 + ml;
      floatx4 xv = *(const floatx4*)xp;
      floatx4 res;
      #pragma unroll
      for (int r = 0; r < 4; ++r) res[r] = acc[ms][cs][r] * linv[r] + xv[r];
      *(floatx4*)(out + ((size_t)b * CC + c) * NN + m0 + ml) = res;
    }
  }
}

// ---------------------------------------------------------------------------
extern "C" void kernel_launch(void* const* d_in, const int* in_sizes, int n_in,
                              void* d_out, int out_size, void* d_ws, size_t ws_size,
                              hipStream_t stream) {
  const float* x     = (const float*)d_in[0];
  const float* Wq    = (const float*)d_in[1];
  const float* bq    = (const float*)d_in[2];
  const float* Wk    = (const float*)d_in[3];
  const float* bk    = (const float*)d_in[4];
  const float* Wv    = (const float*)d_in[5];
  const float* bv    = (const float*)d_in[6];
  const float* gamma = (const float*)d_in[7];
  float* out = (float*)d_out;

  char* ws = (char*)d_ws;
  short* qb = (short*)(ws);                // 2 MB
  short* kb = (short*)(ws + (2u << 20));   // 2 MB
  short* vb = (short*)(ws + (4u << 20));   // 16 MB
  short* Wb = (short*)(ws + (21u << 20));  // 640 KB

  hipLaunchKernelGGL(wconv_kernel, dim3(1280), dim3(256), 0, stream, Wq, Wk, Wv, Wb);
  hipLaunchKernelGGL(qkv_kernel, dim3(640), dim3(512), 0, stream,
                     x, Wb, bq, bk, bv, qb, kb, vb);
  hipLaunchKernelGGL(attn_kernel, dim3(512), dim3(512), 0, stream,
                     qb, kb, vb, x, gamma, out);
}

// Round 8
// 382.301 us; speedup vs baseline: 1.4799x; 1.4799x over previous
//
#include <hip/hip_runtime.h>
#include <hip/hip_bf16.h>

#define BB 4
#define CC 512
#define NN 4096
#define DD 64   // C8

typedef __attribute__((ext_vector_type(8))) short short8;
typedef __attribute__((ext_vector_type(4))) short short4v;
typedef __attribute__((ext_vector_type(4))) float floatx4;

static __device__ __forceinline__ short f2bf(float f) {
  __hip_bfloat16 h = __float2bfloat16(f);
  return *reinterpret_cast<short*>(&h);
}

static __device__ __forceinline__ floatx4 mfma16(short8 a, short8 b, floatx4 c) {
  return __builtin_amdgcn_mfma_f32_16x16x32_bf16(a, b, c, 0, 0, 0);
}

#define GLOAD_LDS16(gp, lp) \
  __builtin_amdgcn_global_load_lds((const __attribute__((address_space(1))) void*)(gp), \
                                   (__attribute__((address_space(3))) void*)(lp), 16, 0, 0)

// ---------------------------------------------------------------------------
// Kernel 0: convert W (Wq rows 0-63, Wk 64-127, Wv 128-639) to bf16 [640][512]
// ---------------------------------------------------------------------------
__global__ void wconv_kernel(const float* __restrict__ Wq, const float* __restrict__ Wk,
                             const float* __restrict__ Wv, short* __restrict__ Wb) {
  int i = blockIdx.x * 256 + threadIdx.x;   // 640*512 = 327680
  int row = i >> 9, c = i & 511;
  float v;
  if (row < 64)        v = Wq[(row << 9) | c];
  else if (row < 128)  v = Wk[((row - 64) << 9) | c];
  else                 v = Wv[((row - 128) << 9) | c];
  Wb[i] = f2bf(v);
}

// ---------------------------------------------------------------------------
// Kernel 1: QKV as 128x128-tile GEMM (unchanged from round 3).
// ---------------------------------------------------------------------------
__global__ __launch_bounds__(512, 4) void qkv_kernel(
    const float* __restrict__ x, const short* __restrict__ Wb,
    const float* __restrict__ bq, const float* __restrict__ bk,
    const float* __restrict__ bv,
    short* __restrict__ qb, short* __restrict__ kb, short* __restrict__ vb) {
  const int bid = blockIdx.x;
  const int jt = bid % 5;
  const int mt = bid / 5;
  const int b  = mt >> 5;
  const int n0 = (mt & 31) << 7;
  const int tid = threadIdx.x;
  const int w = tid >> 6, lane = tid & 63;
  const int arow = lane & 15, grp = lane >> 4;
  const int wm = w >> 2, wj = w & 3;

  __shared__ short xs[128][72];   // [m][k], +8 pad

  const float* xb = x + (size_t)b * CC * NN;
  const int n4l = (tid & 31) << 2;
  const int c4  = (tid >> 5) << 2;

  floatx4 ld[4];
  #pragma unroll
  for (int i = 0; i < 4; ++i)
    ld[i] = *(const floatx4*)(xb + (size_t)(c4 + i) * NN + n0 + n4l);

  floatx4 acc[4][2];
  #pragma unroll
  for (int i = 0; i < 4; ++i)
    #pragma unroll
    for (int j = 0; j < 2; ++j) acc[i][j] = (floatx4){0.f, 0.f, 0.f, 0.f};

  for (int kk = 0; kk < 8; ++kk) {
    __syncthreads();
    #pragma unroll
    for (int j = 0; j < 4; ++j) {
      short4v pk;
      #pragma unroll
      for (int i = 0; i < 4; ++i) pk[i] = f2bf(ld[i][j]);
      *(short4v*)&xs[n4l + j][c4] = pk;
    }
    __syncthreads();
    if (kk < 7) {
      #pragma unroll
      for (int i = 0; i < 4; ++i)
        ld[i] = *(const floatx4*)(xb + (size_t)((kk + 1) * 64 + c4 + i) * NN + n0 + n4l);
    }
    #pragma unroll
    for (int ks = 0; ks < 2; ++ks) {
      short8 pa[4];
      #pragma unroll
      for (int ms = 0; ms < 4; ++ms)
        pa[ms] = *(const short8*)&xs[wm * 64 + ms * 16 + arow][ks * 32 + grp * 8];
      #pragma unroll
      for (int js = 0; js < 2; ++js) {
        const short* wp = Wb + (size_t)(jt * 128 + wj * 32 + js * 16 + arow) * CC
                        + kk * 64 + ks * 32 + grp * 8;
        short8 bfr = *(const short8*)wp;
        #pragma unroll
        for (int ms = 0; ms < 4; ++ms)
          acc[ms][js] = mfma16(pa[ms], bfr, acc[ms][js]);
      }
    }
  }

  #pragma unroll
  for (int js = 0; js < 2; ++js) {
    int dout = jt * 128 + wj * 32 + js * 16 + arow;
    float bias = (dout < 64) ? bq[dout] : (dout < 128) ? bk[dout - 64] : bv[dout - 128];
    #pragma unroll
    for (int ms = 0; ms < 4; ++ms) {
      int n = n0 + wm * 64 + ms * 16 + grp * 4;
      floatx4 a = acc[ms][js];
      if (dout < 64) {
        #pragma unroll
        for (int r = 0; r < 4; ++r)
          qb[((size_t)b * NN + n + r) * DD + dout] = f2bf(a[r] + bias);
      } else if (dout < 128) {
        #pragma unroll
        for (int r = 0; r < 4; ++r)
          kb[((size_t)b * NN + n + r) * DD + (dout - 64)] = f2bf(a[r] + bias);
      } else {
        short4v pk;
        #pragma unroll
        for (int r = 0; r < 4; ++r) pk[r] = f2bf(a[r] + bias);
        *(short4v*)(vb + ((size_t)b * CC + (dout - 128)) * NN + n) = pk;
      }
    }
  }
}

// ---------------------------------------------------------------------------
// Kernel 2: fused attention. v staged in LDS via coalesced global_load_lds
// with chunk-XOR pre-swizzled source (chunk ^= row&7); PV b128 reads are
// bank-uniform. 2 barriers/iter:
//   [PV(i) reads vbuf+pbuf] barA [DMA v(i+1); P1(i+1)->pbuf[(i+1)&1]] barB
// XCD-pinned: bid&7 = (b,ch). Self-normalizing softmax (denominator in regs).
// ---------------------------------------------------------------------------
__global__ __launch_bounds__(512, 4) void attn_kernel(
    const short* __restrict__ qb, const short* __restrict__ kb,
    const short* __restrict__ vb, const float* __restrict__ x,
    const float* __restrict__ gamma, float* __restrict__ out) {
  const int bid = blockIdx.x;
  const int xcd = bid & 7;
  const int b = xcd >> 1, ch = xcd & 1;
  const int m0 = (bid >> 3) << 6;
  const int tid = threadIdx.x;
  const int w = tid >> 6, lane = tid & 63;
  const int arow = lane & 15, grp = lane >> 4;
  const int nsub = w & 3;    // phase1: n-subtile
  const int mh = w >> 2;     // m-half (32 rows)
  const int wc = w & 3;      // phase2: c-quarter (64 ch)

  __shared__ short vbuf[256 * 64];     // 32 KB: [c][n-chunk swizzled]
  __shared__ short pbuf[2][64 * 64];   // 16 KB: P, row-swizzled
  __shared__ float dsum[4][64];

  const short* qB = qb + (size_t)b * NN * DD;
  const short* kB = kb + (size_t)b * NN * DD;
  const short* vB = vb + ((size_t)b * CC + ch * 256) * NN;

  // DMA indexing (wave-uniform LDS base; per-lane swizzled global source)
  const int dma_row = (lane >> 3);            // 0..7 within the 8-row issue
  const int dma_nsw = ((lane & 7) ^ dma_row) << 3;  // swizzled n-offset (shorts)

  // hoisted k fragments for this wave's two m-subtiles
  short8 afr[2][2];
  #pragma unroll
  for (int h = 0; h < 2; ++h) {
    const short* kr = kB + (size_t)(m0 + mh * 32 + h * 16 + arow) * DD;
    afr[h][0] = *(const short8*)(kr + grp * 8);
    afr[h][1] = *(const short8*)(kr + 32 + grp * 8);
  }

  floatx4 acc[2][4];   // [ms][cs]
  #pragma unroll
  for (int i = 0; i < 2; ++i)
    #pragma unroll
    for (int j = 0; j < 4; ++j) acc[i][j] = (floatx4){0.f, 0.f, 0.f, 0.f};
  float dl[2][4];
  #pragma unroll
  for (int h = 0; h < 2; ++h)
    #pragma unroll
    for (int r = 0; r < 4; ++r) dl[h][r] = 0.f;

  short8 qa0, qa1;
  {
    const short* qr = qB + (size_t)(nsub * 16 + arow) * DD + grp * 8;
    qa0 = *(const short8*)(qr);
    qa1 = *(const short8*)(qr + 32);
  }

  // prologue: DMA v(0), P1(0) -> pbuf[0], prefetch qa(1)
  #pragma unroll
  for (int q = 0; q < 4; ++q) {
    int r = w * 32 + q * 8 + dma_row;
    GLOAD_LDS16(vB + (size_t)r * NN + dma_nsw, vbuf + (w * 32 + q * 8) * 64);
  }
  #pragma unroll
  for (int h = 0; h < 2; ++h) {
    floatx4 s4 = (floatx4){0.f, 0.f, 0.f, 0.f};
    s4 = mfma16(afr[h][0], qa0, s4);
    s4 = mfma16(afr[h][1], qa1, s4);
    int mrow = mh * 32 + h * 16 + grp * 4;
    #pragma unroll
    for (int r = 0; r < 4; ++r) {
      float p = __expf(s4[r]);
      dl[h][r] += p;
      int row = mrow + r;
      pbuf[0][row * 64 + ((nsub * 16 + arow) ^ ((row & 7) << 3))] = f2bf(p);
    }
  }
  {
    const short* qr = qB + (size_t)(64 + nsub * 16 + arow) * DD + grp * 8;
    qa0 = *(const short8*)(qr);
    qa1 = *(const short8*)(qr + 32);
  }
  __syncthreads();   // v(0) landed, P(0) visible

  // per-lane read bases
  const int vbase0 = (wc * 64 + arow) * 64 + ((grp ^ (arow & 7)) << 3);  // shorts, ks=0
  for (int i = 0; i < 64; ++i) {
    // ---- PV(i): read pbuf[i&1] + vbuf, 16 MFMA ----
    {
      short8 pa[2][2];
      #pragma unroll
      for (int ms = 0; ms < 2; ++ms) {
        int row = mh * 32 + ms * 16 + arow;
        #pragma unroll
        for (int ks = 0; ks < 2; ++ks)
          pa[ms][ks] = *(const short8*)&pbuf[i & 1][row * 64 + ((ks * 32 + grp * 8) ^ ((row & 7) << 3))];
      }
      short8 vv0[4], vv1[4];
      #pragma unroll
      for (int cs = 0; cs < 4; ++cs) {
        vv0[cs] = *(const short8*)&vbuf[vbase0 + cs * 16 * 64];
        vv1[cs] = *(const short8*)&vbuf[(vbase0 + cs * 16 * 64) ^ 32];  // chunk ^4 = ^64B = ^32 shorts
      }
      __builtin_amdgcn_s_setprio(1);
      #pragma unroll
      for (int cs = 0; cs < 4; ++cs)
        #pragma unroll
        for (int ms = 0; ms < 2; ++ms)
          acc[ms][cs] = mfma16(pa[ms][0], vv0[cs], acc[ms][cs]);
      #pragma unroll
      for (int cs = 0; cs < 4; ++cs)
        #pragma unroll
        for (int ms = 0; ms < 2; ++ms)
          acc[ms][cs] = mfma16(pa[ms][1], vv1[cs], acc[ms][cs]);
      __builtin_amdgcn_s_setprio(0);
    }
    __syncthreads();   // barA: all reads of vbuf / pbuf[i&1] done
    if (i < 63) {
      const int nb1 = (i + 1) << 6;
      // DMA v(i+1) (overlaps with P1 below; drained at barB)
      #pragma unroll
      for (int q = 0; q < 4; ++q) {
        int r = w * 32 + q * 8 + dma_row;
        GLOAD_LDS16(vB + (size_t)r * NN + nb1 + dma_nsw, vbuf + (w * 32 + q * 8) * 64);
      }
      // P1(i+1) -> pbuf[(i+1)&1]
      #pragma unroll
      for (int h = 0; h < 2; ++h) {
        floatx4 s4 = (floatx4){0.f, 0.f, 0.f, 0.f};
        s4 = mfma16(afr[h][0], qa0, s4);
        s4 = mfma16(afr[h][1], qa1, s4);
        int mrow = mh * 32 + h * 16 + grp * 4;
        #pragma unroll
        for (int r = 0; r < 4; ++r) {
          float p = __expf(s4[r]);
          dl[h][r] += p;
          int row = mrow + r;
          pbuf[(i + 1) & 1][row * 64 + ((nsub * 16 + arow) ^ ((row & 7) << 3))] = f2bf(p);
        }
      }
      if (i < 62) {
        const short* qr = qB + (size_t)(nb1 + 64 + nsub * 16 + arow) * DD + grp * 8;
        qa0 = *(const short8*)(qr);
        qa1 = *(const short8*)(qr + 32);
      }
    }
    __syncthreads();   // barB: v(i+1) landed, P(i+1) visible
  }

  // denominator: reduce dl over the 16 arow lanes; combine 4 nsub partials
  #pragma unroll
  for (int off = 1; off < 16; off <<= 1)
    #pragma unroll
    for (int h = 0; h < 2; ++h)
      #pragma unroll
      for (int r = 0; r < 4; ++r)
        dl[h][r] += __shfl_xor(dl[h][r], off);
  if (arow == 0) {
    #pragma unroll
    for (int h = 0; h < 2; ++h)
      #pragma unroll
      for (int r = 0; r < 4; ++r)
        dsum[nsub][mh * 32 + h * 16 + grp * 4 + r] = dl[h][r];
  }
  __syncthreads();

  const float g = *gamma;
  #pragma unroll
  for (int ms = 0; ms < 2; ++ms) {
    int ml = mh * 32 + ms * 16 + grp * 4;
    floatx4 linv;
    #pragma unroll
    for (int r = 0; r < 4; ++r) {
      float l = dsum[0][ml + r] + dsum[1][ml + r] + dsum[2][ml + r] + dsum[3][ml + r];
      linv[r] = g / l;
    }
    #pragma unroll
    for (int cs = 0; cs < 4; ++cs) {
      int c = ch * 256 + wc * 64 + cs * 16 + arow;
      const float* xp = x + ((size_t)b * CC + c) * NN + m0 + ml;
      floatx4 xv = *(const floatx4*)xp;
      floatx4 res;
      #pragma unroll
      for (int r = 0; r < 4; ++r) res[r] = acc[ms][cs][r] * linv[r] + xv[r];
      *(floatx4*)(out + ((size_t)b * CC + c) * NN + m0 + ml) = res;
    }
  }
}

// ---------------------------------------------------------------------------
extern "C" void kernel_launch(void* const* d_in, const int* in_sizes, int n_in,
                              void* d_out, int out_size, void* d_ws, size_t ws_size,
                              hipStream_t stream) {
  const float* x     = (const float*)d_in[0];
  const float* Wq    = (const float*)d_in[1];
  const float* bq    = (const float*)d_in[2];
  const float* Wk    = (const float*)d_in[3];
  const float* bk    = (const float*)d_in[4];
  const float* Wv    = (const float*)d_in[5];
  const float* bv    = (const float*)d_in[6];
  const float* gamma = (const float*)d_in[7];
  float* out = (float*)d_out;

  char* ws = (char*)d_ws;
  short* qb = (short*)(ws);                // 2 MB
  short* kb = (short*)(ws + (2u << 20));   // 2 MB
  short* vb = (short*)(ws + (4u << 20));   // 16 MB
  short* Wb = (short*)(ws + (21u << 20));  // 640 KB

  hipLaunchKernelGGL(wconv_kernel, dim3(1280), dim3(256), 0, stream, Wq, Wk, Wv, Wb);
  hipLaunchKernelGGL(qkv_kernel, dim3(640), dim3(512), 0, stream,
                     x, Wb, bq, bk, bv, qb, kb, vb);
  hipLaunchKernelGGL(attn_kernel, dim3(512), dim3(512), 0, stream,
                     qb, kb, vb, x, gamma, out);
}